// Round 6
// baseline (331.758 us; speedup 1.0000x reference)
//
#include <hip/hip_runtime.h>

// QuerySelector: B=8 LQ=1024 S=256 D=1024 H=16 HD=64.
// R14: extend R13's proven 4-blocks/CU mechanism to the kernels stuck at
// 2/CU: (a) h1box/w2gemm 128x128/BK=128/512blk -> 128x64/BK=64/1024blk
// (LDS 24KB, (256,4)); box head 8 rows/block, 32-lane split-K. (b) attn:
// drop K/V LDS staging (L2-resident: 64KB/head shared by 16 swizzled
// blocks; waves issue identical addresses -> L1); direct global MFMA
// fragment reads; LDS = P only (32KB) -> (256,4), 1 barrier. qkvwf
// unchanged (R13 control: 45.6us, MfmaUtil 23%, FETCH 45.8MB).

typedef unsigned short u16;
typedef unsigned int u32;
typedef __bf16 bf16x8 __attribute__((ext_vector_type(8)));
typedef float f32x4 __attribute__((ext_vector_type(4)));
typedef u16 u16x4 __attribute__((ext_vector_type(4)));

struct CvtArgs { const void* in[15]; };

__device__ __forceinline__ u16 f2bf(float f) {
  u32 u = __builtin_bit_cast(u32, f);
  u += 0x7fffu + ((u >> 16) & 1u);   // RNE
  return (u16)(u >> 16);
}
__device__ __forceinline__ float bf2f(u16 h) {
  u32 u = ((u32)h) << 16;
  return __builtin_bit_cast(float, u);
}

// ---------------- workspace layout (u16 offsets) ----------------
struct WsPtrs {
  u16 *c_mem, *c_gaze, *c_text, *c_win, *c_bin, *c_wo, *c_bo, *c_w1, *c_b1,
      *c_w2, *c_b2, *c_g1, *c_be1, *c_g2, *c_be2;
  u16 *q, *k, *v, *ctx, *woT, *wf, *bfb, *h1, *ffnb;
};
__device__ __forceinline__ WsPtrs wsp(u16* C) {
  WsPtrs w;
  w.c_mem = C;                 w.c_gaze = C + 4194304;   w.c_text = C + 8388608;
  w.c_win = C + 10485760;      w.c_bin = C + 13631488;   w.c_wo = C + 13634560;
  w.c_bo = C + 14683136;       w.c_w1 = C + 14684160;    w.c_b1 = C + 15732736;
  w.c_w2 = C + 15733760;       w.c_b2 = C + 16782336;    w.c_g1 = C + 16783360;
  w.c_be1 = C + 16784384;      w.c_g2 = C + 16785408;    w.c_be2 = C + 16786432;
  u16* B2 = C + 16787488;
  w.q = B2;                    w.k = B2 + 8388608;       w.v = B2 + 10485760;
  w.ctx = B2 + 12582912;
  w.woT = B2 + 20971520;       // dead after qkvwf
  w.wf  = B2 + 22020096;
  w.bfb = B2 + 23068672;
  w.h1  = B2 + 29360128;
  w.ffnb = B2;                 // bf16 ffn over dead q slot (q dead after attn)
  return w;
}

// ---------------- P0: stage inputs to bf16 + transpose Wo ----------------
__device__ __forceinline__ void cvt_chunk(bool f32in, u16* dst,
                                          const void* const* srcs, u32 c8) {
  const u32 cum[16] = {0u, 4194304u, 8388608u, 10485760u, 13631488u, 13634560u,
                       14683136u, 14684160u, 15732736u, 15733760u, 16782336u,
                       16783360u, 16784384u, 16785408u, 16786432u, 16787456u};
  u32 base = c8 * 8u;
  int idx = 0;
#pragma unroll
  for (int i = 1; i < 15; ++i) if (base >= cum[i]) idx = i;
  u32 off = base - cum[idx];
  if (f32in) {
    const float* s = (const float*)srcs[idx] + off;
    float4 a = ((const float4*)s)[0];
    float4 b = ((const float4*)s)[1];
    u16 t[8] = {f2bf(a.x), f2bf(a.y), f2bf(a.z), f2bf(a.w),
                f2bf(b.x), f2bf(b.y), f2bf(b.z), f2bf(b.w)};
    *(uint4*)(dst + base) = *(const uint4*)t;
  } else {
    *(uint4*)(dst + base) = *(const uint4*)((const u16*)srcs[idx] + off);
  }
}

__global__ __launch_bounds__(256) void cvt_tr(CvtArgs a, u16* ws) {
  __shared__ u16 tile[128 * 136];
  const bool f32in = (((const u32*)a.in[11])[0] == 0x3F800000u);
  const int bid = blockIdx.x, tid = threadIdx.x;
  if (bid < 64) {
    WsPtrs w = wsp(ws);
    int tr = bid >> 3, tc = bid & 7;
#pragma unroll
    for (int p = 0; p < 8; ++p) {
      int t = p * 16 + (tid >> 4);
      int j8 = (tid & 15) * 8;
      u16 tmp[8];
      if (f32in) {
        const float* s = (const float*)a.in[5] + (size_t)(tr * 128 + t) * 1024 + tc * 128 + j8;
        float4 x = ((const float4*)s)[0], y = ((const float4*)s)[1];
        tmp[0]=f2bf(x.x); tmp[1]=f2bf(x.y); tmp[2]=f2bf(x.z); tmp[3]=f2bf(x.w);
        tmp[4]=f2bf(y.x); tmp[5]=f2bf(y.y); tmp[6]=f2bf(y.z); tmp[7]=f2bf(y.w);
      } else {
        *(uint4*)tmp = *(const uint4*)((const u16*)a.in[5] + (size_t)(tr * 128 + t) * 1024 + tc * 128 + j8);
      }
      *(uint4*)&tile[t * 136 + j8] = *(const uint4*)tmp;
    }
    __syncthreads();
#pragma unroll
    for (int p = 0; p < 8; ++p) {
      int j = p * 16 + (tid >> 4);
      int t8 = (tid & 15) * 8;
      u16 tmp[8];
#pragma unroll
      for (int i = 0; i < 8; ++i) tmp[i] = tile[(t8 + i) * 136 + j];
      *(uint4*)(w.woT + (size_t)(tc * 128 + j) * 1024 + tr * 128 + t8) = *(const uint4*)tmp;
    }
  } else {
    u32 c8 = (u32)(bid - 64) * 256u + tid;
    if (c8 < 2098432u) cvt_chunk(f32in, ws, a.in, c8);
  }
}

// ---------------- GEMM tile core, template TN in {128,64}, BK=64 ----------
// C[M,N] = A[M,K]*W[N,K]^T + bias. 128xTN tile, 4 waves (2x2), wave
// 64x(TN/2) via 4x(TN/32) mfma 16x16x32, 2 K-slices per step.
// LDS = 16KB(A) + TN*128 B(B). global_load_lds dwordx4 staging, XOR swizzle
// on SOURCE address (LDS dest linear, wave-uniform base); swizzled
// ds_read_b128 fragments, conflict-free.
// Modes: 0 bf16; 1 +relu bf16; 3 head-transpose (L=1<<lg); 4 v-transpose.
template <int TN>
__device__ __forceinline__ void gemm_core(
    u16* sA, u16* sB,
    const u16* A0, const u16* A1, int Ksplit, int lda0, int lda1,
    const u16* W, const u16* bias, void* out, int N, int K,
    int mode, int lg, int m0, int n0)
{
  constexpr int JN = TN >> 5;     // B frags per wave (4 or 2)
  constexpr int BCPT = TN >> 5;   // B chunks per thread (4 or 2)
  const int tid = threadIdx.x;
  const int wave = tid >> 6, lane = tid & 63;
  const int quad = lane >> 4, l16 = lane & 15;
  const int wm = wave >> 1, wn = wave & 1;

  f32x4 acc[4][JN];
#pragma unroll
  for (int i = 0; i < 4; ++i)
#pragma unroll
    for (int j = 0; j < JN; ++j) acc[i][j] = (f32x4){0.f, 0.f, 0.f, 0.f};

  for (int k0 = 0; k0 < K; k0 += 64) {
#pragma unroll
    for (int qi = 0; qi < 4; ++qi) {       // A: 128 rows x 8 chunks
      int p = (wave * 4 + qi) * 64 + lane;
      int row = p >> 3;
      int c = (p & 7) ^ (row & 7);
      int gk = k0 + (c << 3);
      const u16* srcA = (gk < Ksplit) ? (A0 + (size_t)(m0 + row) * lda0 + gk)
                                      : (A1 + (size_t)(m0 + row) * lda1 + (gk - Ksplit));
      __builtin_amdgcn_global_load_lds(
          (const __attribute__((address_space(1))) void*)srcA,
          (__attribute__((address_space(3))) void*)&sA[(size_t)(wave * 4 + qi) * 512],
          16, 0, 0);
    }
#pragma unroll
    for (int qi = 0; qi < BCPT; ++qi) {    // B: TN rows x 8 chunks
      int p = (wave * BCPT + qi) * 64 + lane;
      int row = p >> 3;
      int c = (p & 7) ^ (row & 7);
      int gk = k0 + (c << 3);
      const u16* srcB = W + (size_t)(n0 + row) * K + gk;
      __builtin_amdgcn_global_load_lds(
          (const __attribute__((address_space(1))) void*)srcB,
          (__attribute__((address_space(3))) void*)&sB[(size_t)(wave * BCPT + qi) * 512],
          16, 0, 0);
    }
    __syncthreads();
#pragma unroll
    for (int ks = 0; ks < 2; ++ks) {
      const int ch = (ks << 2) + quad;
      bf16x8 af[4], bw[JN];
#pragma unroll
      for (int i = 0; i < 4; ++i) {
        int row = wm * 64 + i * 16 + l16;
        af[i] = *(const bf16x8*)&sA[(row << 6) + ((ch ^ (row & 7)) << 3)];
      }
#pragma unroll
      for (int j = 0; j < JN; ++j) {
        int row = wn * (TN >> 1) + j * 16 + l16;
        bw[j] = *(const bf16x8*)&sB[(row << 6) + ((ch ^ (row & 7)) << 3)];
      }
#pragma unroll
      for (int i = 0; i < 4; ++i)
#pragma unroll
        for (int j = 0; j < JN; ++j)
          acc[i][j] = __builtin_amdgcn_mfma_f32_16x16x32_bf16(af[i], bw[j], acc[i][j], 0, 0, 0);
    }
    __syncthreads();
  }

  // C/D layout: col = l16, row = quad*4 + rr (verified m89/m91)
#pragma unroll
  for (int i = 0; i < 4; ++i) {
#pragma unroll
    for (int j = 0; j < JN; ++j) {
      int n = n0 + wn * (TN >> 1) + j * 16 + l16;
      float bv = bias ? bf2f(bias[n]) : 0.f;
#pragma unroll
      for (int rr = 0; rr < 4; ++rr) {
        int m = m0 + wm * 64 + i * 16 + quad * 4 + rr;
        float val = acc[i][j][rr] + bv;
        if (mode == 1) val = fmaxf(val, 0.f);
        if (mode <= 1) {
          ((u16*)out)[(size_t)m * N + n] = f2bf(val);
        } else if (mode == 3) {
          int b = m >> lg, l = m & ((1 << lg) - 1);
          int h = n >> 6, d = n & 63;
          ((u16*)out)[((size_t)((b * 16 + h)) << (lg + 6)) + (l << 6) + d] = f2bf(val);
        } else {
          int b = m >> lg, s = m & ((1 << lg) - 1);
          int h = n >> 6, d = n & 63;
          ((u16*)out)[((size_t)(((b * 16 + h) << 6) + d) << lg) + s] = f2bf(val);
        }
      }
    }
  }
}

// XCD chunked swizzle: blocks bid%8==c (one XCD under round-robin dispatch)
// get a contiguous u-range -> per-XCD L2 working set ~4MB. n%8==0 required.
__device__ __forceinline__ int xswz(int u, int n8) {  // n8 = nblk/8
  return (u & 7) * n8 + (u >> 3);
}

// P1: 836 blocks. 0..511 Q, 512..639 K, 640..767 V, 768..831 Wf, 832..835 bf.
__global__ __launch_bounds__(256, 4) void qkvwf(u16* ws) {
  __shared__ __align__(16) u16 lds[16384];
  WsPtrs w = wsp(ws);
  const int bid = blockIdx.x, tid = threadIdx.x;
  if (bid < 512) {
    int u = xswz(bid, 64);
    gemm_core<128>(lds, lds + 8192, w.c_mem, w.c_gaze, 512, 512, 512,
                   w.c_win, w.c_bin, w.q, 1024, 1024, 3, 10,
                   (u >> 3) * 128, (u & 7) * 128);
  } else if (bid < 640) {
    int u = xswz(bid - 512, 16);
    gemm_core<128>(lds, lds + 8192, w.c_text, w.c_text, 1024, 1024, 1024,
                   w.c_win + 1048576, w.c_bin + 1024, w.k, 1024, 1024, 3, 8,
                   (u >> 3) * 128, (u & 7) * 128);
  } else if (bid < 768) {
    int u = xswz(bid - 640, 16);
    gemm_core<128>(lds, lds + 8192, w.c_text, w.c_text, 1024, 1024, 1024,
                   w.c_win + 2097152, w.c_bin + 2048, w.v, 1024, 1024, 4, 8,
                   (u >> 3) * 128, (u & 7) * 128);
  } else if (bid < 832) {
    int u = xswz(bid - 768, 8);
    gemm_core<128>(lds, lds + 8192, w.c_w1, w.c_w1, 1024, 1024, 1024,
                   w.woT, nullptr, w.wf, 1024, 1024, 0, 0,
                   (u >> 3) * 128, (u & 7) * 128);
  } else {
    // bf[i] = b1[i] + sum_t W1[i,t]*bo[t]
    int i = (bid - 832) * 256 + tid;
    const u16* w1row = w.c_w1 + (size_t)i * 1024;
    float acc = bf2f(w.c_b1[i]);
    for (int kk = 0; kk < 1024; kk += 8) {
      bf16x8 wv = *(const bf16x8*)(w1row + kk);
      bf16x8 bv = *(const bf16x8*)(w.c_bo + kk);
#pragma unroll
      for (int j = 0; j < 8; ++j) acc += (float)wv[j] * (float)bv[j];
    }
    w.bfb[i] = f2bf(acc);
  }
}

// ---------------- P2: attention tile (b,h) x 64 queries ----------------
// K/V read directly from global (L2-resident: 16 swizzled blocks share each
// 64KB head; all 4 waves issue identical K/V addresses -> L1). LDS = P only.
__global__ __launch_bounds__(256, 4) void attn_kernel(u16* ws) {
  __shared__ u16 sP[64 * 256];   // 32KB
  WsPtrs w = wsp(ws);
  const int tid = threadIdx.x;
  const int wave = tid >> 6, lane = tid & 63;
  const int quad = lane >> 4, l16 = lane & 15;
  const int su = xswz(blockIdx.x, 256);
  const int qb = su & 15, bh = su >> 4;
  const u16* kb = w.k + (size_t)bh * 16384;   // [s][d]
  const u16* vb = w.v + (size_t)bh * 16384;   // [d][s]

  bf16x8 aq[2];
  {
    const u16* qrow = w.q + ((size_t)bh * 1024 + qb * 64 + wave * 16 + l16) * 64 + quad * 8;
    aq[0] = *(const bf16x8*)(qrow);
    aq[1] = *(const bf16x8*)(qrow + 32);
  }

  f32x4 sc[16];
#pragma unroll
  for (int nt = 0; nt < 16; ++nt) sc[nt] = (f32x4){0.f, 0.f, 0.f, 0.f};
  __builtin_amdgcn_s_setprio(1);
#pragma unroll
  for (int ks = 0; ks < 2; ++ks) {
    const int ch = (ks << 2) + quad;
#pragma unroll
    for (int nt = 0; nt < 16; ++nt) {
      int row = nt * 16 + l16;
      bf16x8 bk = *(const bf16x8*)(kb + (size_t)row * 64 + ch * 8);
      sc[nt] = __builtin_amdgcn_mfma_f32_16x16x32_bf16(aq[ks], bk, sc[nt], 0, 0, 0);
    }
  }
  __builtin_amdgcn_s_setprio(0);
#pragma unroll
  for (int rr = 0; rr < 4; ++rr) {
    float mx = -1e30f;
#pragma unroll
    for (int nt = 0; nt < 16; ++nt) mx = fmaxf(mx, sc[nt][rr]);
    for (int off = 1; off < 16; off <<= 1) mx = fmaxf(mx, __shfl_xor(mx, off, 64));
    float sum = 0.f;
#pragma unroll
    for (int nt = 0; nt < 16; ++nt) {
      float p = __expf((sc[nt][rr] - mx) * 0.125f);
      sc[nt][rr] = p; sum += p;
    }
    for (int off = 1; off < 16; off <<= 1) sum += __shfl_xor(sum, off, 64);
    float inv = 1.f / sum;
#pragma unroll
    for (int nt = 0; nt < 16; ++nt) sc[nt][rr] *= inv;
  }
#pragma unroll
  for (int nt = 0; nt < 16; ++nt)
#pragma unroll
    for (int rr = 0; rr < 4; ++rr) {
      int row = wave * 16 + quad * 4 + rr;
      int col = nt * 16 + l16;
      sP[(row << 8) + (((col >> 3) ^ (row & 7)) << 3) + (col & 7)] = f2bf(sc[nt][rr]);
    }
  __syncthreads();

  f32x4 o[4];
#pragma unroll
  for (int j = 0; j < 4; ++j) o[j] = (f32x4){0.f, 0.f, 0.f, 0.f};
  __builtin_amdgcn_s_setprio(1);
#pragma unroll
  for (int ks = 0; ks < 8; ++ks) {
    const int ch = (ks << 2) + quad;   // 0..31 s-chunk
    int prow = wave * 16 + l16;
    bf16x8 ap = *(const bf16x8*)&sP[(prow << 8) + ((ch ^ (prow & 7)) << 3)];
#pragma unroll
    for (int j = 0; j < 4; ++j) {
      int vrow = j * 16 + l16;           // d
      bf16x8 bv = *(const bf16x8*)(vb + (size_t)vrow * 256 + ch * 8);
      o[j] = __builtin_amdgcn_mfma_f32_16x16x32_bf16(ap, bv, o[j], 0, 0, 0);
    }
  }
  __builtin_amdgcn_s_setprio(0);
  const int b = bh >> 4, h = bh & 15;
#pragma unroll
  for (int j = 0; j < 4; ++j)
#pragma unroll
    for (int rr = 0; rr < 4; ++rr) {
      int m = qb * 64 + wave * 16 + quad * 4 + rr;
      int d = h * 64 + j * 16 + l16;
      w.ctx[((size_t)b * 1024 + m) * 1024 + d] = f2bf(o[j][rr]);
    }
}

// P3: 1024 blocks. Each block: box for 8 rows (32-lane split-K) + one
// 128x64 h1 tile (BK=64, 24KB LDS, 4 blocks/CU).
__global__ __launch_bounds__(256, 4) void h1box(u16* ws, void* out, const void* g1orig) {
  __shared__ __align__(16) u16 lds[12288];
  WsPtrs w = wsp(ws);
  const int u = blockIdx.x, tid = threadIdx.x;
  {
    const bool f32out = (((const u32*)g1orig)[0] == 0x3F800000u);
    int m = u * 8 + (tid >> 5);
    int l32 = tid & 31;
    int k0 = l32 * 32;
    const u16* crow = w.ctx + (size_t)m * 1024 + k0;
    float a0 = 0.f, a1 = 0.f, a2 = 0.f, a3 = 0.f;
#pragma unroll
    for (int kk = 0; kk < 32; kk += 8) {
      bf16x8 cv = *(const bf16x8*)(crow + kk);
      bf16x8 w0 = *(const bf16x8*)(w.c_wo + k0 + kk);
      bf16x8 w1v = *(const bf16x8*)(w.c_wo + 1024 + k0 + kk);
      bf16x8 w2v = *(const bf16x8*)(w.c_wo + 2048 + k0 + kk);
      bf16x8 w3v = *(const bf16x8*)(w.c_wo + 3072 + k0 + kk);
#pragma unroll
      for (int j = 0; j < 8; ++j) {
        float c = (float)cv[j];
        a0 += c * (float)w0[j]; a1 += c * (float)w1v[j];
        a2 += c * (float)w2v[j]; a3 += c * (float)w3v[j];
      }
    }
    for (int off = 1; off < 32; off <<= 1) {
      a0 += __shfl_xor(a0, off, 64); a1 += __shfl_xor(a1, off, 64);
      a2 += __shfl_xor(a2, off, 64); a3 += __shfl_xor(a3, off, 64);
    }
    if (l32 == 0) {
      a0 += bf2f(w.c_bo[0]); a1 += bf2f(w.c_bo[1]);
      a2 += bf2f(w.c_bo[2]); a3 += bf2f(w.c_bo[3]);
      float s0 = 1.f / (1.f + __expf(-a0)), s1 = 1.f / (1.f + __expf(-a1));
      float s2 = 1.f / (1.f + __expf(-a2)), s3 = 1.f / (1.f + __expf(-a3));
      float o0 = s0 - s2 * 0.5f, o1 = s1 - s3 * 0.5f;
      float o2 = s0 + s2 * 0.5f, o3 = s1 + s3 * 0.5f;
      if (f32out) {
        float* fo = (float*)out + 16777216;
        *(float4*)(fo + (size_t)m * 4) = make_float4(o0, o1, o2, o3);
      } else {
        u16* bo = (u16*)out + 16777216;
        u16x4 o; o[0] = f2bf(o0); o[1] = f2bf(o1); o[2] = f2bf(o2); o[3] = f2bf(o3);
        *(u16x4*)(bo + (size_t)m * 4) = o;
      }
    }
  }
  int us = xswz(u, 128);
  gemm_core<64>(lds, lds + 8192, w.ctx, w.ctx, 1024, 1024, 1024,
                w.wf, w.bfb, w.h1, 1024, 1024, 1, 0,
                (us >> 4) * 128, (us & 15) * 64);
}

// P4: ffnb = h1 @ w2^T + b2 (bf16 out). 1024 blocks, 128x64 tiles.
__global__ __launch_bounds__(256, 4) void w2gemm(u16* ws) {
  __shared__ __align__(16) u16 lds[12288];
  WsPtrs w = wsp(ws);
  int us = xswz((int)blockIdx.x, 128);
  gemm_core<64>(lds, lds + 8192, w.h1, w.h1, 1024, 1024, 1024,
                w.c_w2, w.c_b2, w.ffnb, 1024, 1024, 0, 0,
                (us >> 4) * 128, (us & 15) * 64);
}

// P5: LayerNorm x2 over ffnb bf16 [8192][1024]; dual-dtype output.
__global__ __launch_bounds__(256) void ln_kernel(u16* ws, void* outv, const void* g1orig) {
  WsPtrs w = wsp(ws);
  const bool f32out = (((const u32*)g1orig)[0] == 0x3F800000u);
  const int row = blockIdx.x, tid = threadIdx.x;
  int c = tid * 4;
  u16x4 xr = *(const u16x4*)(w.ffnb + (size_t)row * 1024 + c);
  float x[4] = {bf2f(xr[0]), bf2f(xr[1]), bf2f(xr[2]), bf2f(xr[3])};
  float s = x[0] + x[1] + x[2] + x[3];
  float s2 = x[0]*x[0] + x[1]*x[1] + x[2]*x[2] + x[3]*x[3];
  for (int m = 32; m >= 1; m >>= 1) { s += __shfl_xor(s, m, 64); s2 += __shfl_xor(s2, m, 64); }
  __shared__ float red[8];
  int wv = tid >> 6;
  if ((tid & 63) == 0) { red[wv] = s; red[4 + wv] = s2; }
  __syncthreads();
  s = red[0] + red[1] + red[2] + red[3];
  s2 = red[4] + red[5] + red[6] + red[7];
  float mean = s * (1.f / 1024.f);
  float var = s2 * (1.f / 1024.f) - mean * mean;
  float inv = rsqrtf(var + 1e-5f);
  float y[4] = {(x[0] - mean) * inv, (x[1] - mean) * inv, (x[2] - mean) * inv, (x[3] - mean) * inv};
  float v1[4], v2[4];
#pragma unroll
  for (int i = 0; i < 4; ++i) {
    v1[i] = y[i] * bf2f(w.c_g1[c + i]) + bf2f(w.c_be1[c + i]);
    v2[i] = y[i] * bf2f(w.c_g2[c + i]) + bf2f(w.c_be2[c + i]);
  }
  if (f32out) {
    float* fo = (float*)outv;
    *(float4*)(fo + (size_t)row * 1024 + c) = make_float4(v1[0], v1[1], v1[2], v1[3]);
    *(float4*)(fo + 8388608 + (size_t)row * 1024 + c) = make_float4(v2[0], v2[1], v2[2], v2[3]);
  } else {
    u16* out = (u16*)outv;
    u16x4 o1, o2;
#pragma unroll
    for (int i = 0; i < 4; ++i) { o1[i] = f2bf(v1[i]); o2[i] = f2bf(v2[i]); }
    *(u16x4*)(out + (size_t)row * 1024 + c) = o1;
    *(u16x4*)(out + 8388608 + (size_t)row * 1024 + c) = o2;
  }
}

extern "C" void kernel_launch(void* const* d_in, const int* in_sizes, int n_in,
                              void* d_out, int out_size, void* d_ws, size_t ws_size,
                              hipStream_t stream) {
  CvtArgs ca;
  for (int i = 0; i < 15; ++i) ca.in[i] = d_in[i];
  u16* ws = (u16*)d_ws;
  dim3 blk(256);
  cvt_tr<<<dim3(8261), blk, 0, stream>>>(ca, ws);
  qkvwf<<<dim3(836), blk, 0, stream>>>(ws);
  attn_kernel<<<dim3(2048), blk, 0, stream>>>(ws);
  h1box<<<dim3(1024), blk, 0, stream>>>(ws, d_out, d_in[11]);
  w2gemm<<<dim3(1024), blk, 0, stream>>>(ws);
  ln_kernel<<<dim3(8192), blk, 0, stream>>>(ws, d_out, d_in[11]);
}

// Round 7
// 287.578 us; speedup vs baseline: 1.1536x; 1.1536x over previous
//
#include <hip/hip_runtime.h>

// QuerySelector: B=8 LQ=1024 S=256 D=1024 H=16 HD=64.
// R15: A/B isolation. attn reverted to R13's staged form (R14's direct-global
// K/V was latency-bound: MfmaUtil 4.5%, 70us - each MFMA depended on a fresh
// ~200cy L2 load; staging is a latency-decoupler even when data L2-fits).
// KEPT from R14: h1box/w2gemm at 128x64/BK=64/1024blk/(256,4) = 4 blocks/CU
// (not falsified by R14; isolated here against R13's 289.4us baseline).
// qkvwf unchanged control (45.6us, FETCH 45.8MB).

typedef unsigned short u16;
typedef unsigned int u32;
typedef __bf16 bf16x8 __attribute__((ext_vector_type(8)));
typedef float f32x4 __attribute__((ext_vector_type(4)));
typedef u16 u16x4 __attribute__((ext_vector_type(4)));

struct CvtArgs { const void* in[15]; };

__device__ __forceinline__ u16 f2bf(float f) {
  u32 u = __builtin_bit_cast(u32, f);
  u += 0x7fffu + ((u >> 16) & 1u);   // RNE
  return (u16)(u >> 16);
}
__device__ __forceinline__ float bf2f(u16 h) {
  u32 u = ((u32)h) << 16;
  return __builtin_bit_cast(float, u);
}

// ---------------- workspace layout (u16 offsets) ----------------
struct WsPtrs {
  u16 *c_mem, *c_gaze, *c_text, *c_win, *c_bin, *c_wo, *c_bo, *c_w1, *c_b1,
      *c_w2, *c_b2, *c_g1, *c_be1, *c_g2, *c_be2;
  u16 *q, *k, *v, *ctx, *woT, *wf, *bfb, *h1, *ffnb;
};
__device__ __forceinline__ WsPtrs wsp(u16* C) {
  WsPtrs w;
  w.c_mem = C;                 w.c_gaze = C + 4194304;   w.c_text = C + 8388608;
  w.c_win = C + 10485760;      w.c_bin = C + 13631488;   w.c_wo = C + 13634560;
  w.c_bo = C + 14683136;       w.c_w1 = C + 14684160;    w.c_b1 = C + 15732736;
  w.c_w2 = C + 15733760;       w.c_b2 = C + 16782336;    w.c_g1 = C + 16783360;
  w.c_be1 = C + 16784384;      w.c_g2 = C + 16785408;    w.c_be2 = C + 16786432;
  u16* B2 = C + 16787488;
  w.q = B2;                    w.k = B2 + 8388608;       w.v = B2 + 10485760;
  w.ctx = B2 + 12582912;
  w.woT = B2 + 20971520;       // dead after qkvwf
  w.wf  = B2 + 22020096;
  w.bfb = B2 + 23068672;
  w.h1  = B2 + 29360128;
  w.ffnb = B2;                 // bf16 ffn over dead q slot (q dead after attn)
  return w;
}

// ---------------- P0: stage inputs to bf16 + transpose Wo ----------------
__device__ __forceinline__ void cvt_chunk(bool f32in, u16* dst,
                                          const void* const* srcs, u32 c8) {
  const u32 cum[16] = {0u, 4194304u, 8388608u, 10485760u, 13631488u, 13634560u,
                       14683136u, 14684160u, 15732736u, 15733760u, 16782336u,
                       16783360u, 16784384u, 16785408u, 16786432u, 16787456u};
  u32 base = c8 * 8u;
  int idx = 0;
#pragma unroll
  for (int i = 1; i < 15; ++i) if (base >= cum[i]) idx = i;
  u32 off = base - cum[idx];
  if (f32in) {
    const float* s = (const float*)srcs[idx] + off;
    float4 a = ((const float4*)s)[0];
    float4 b = ((const float4*)s)[1];
    u16 t[8] = {f2bf(a.x), f2bf(a.y), f2bf(a.z), f2bf(a.w),
                f2bf(b.x), f2bf(b.y), f2bf(b.z), f2bf(b.w)};
    *(uint4*)(dst + base) = *(const uint4*)t;
  } else {
    *(uint4*)(dst + base) = *(const uint4*)((const u16*)srcs[idx] + off);
  }
}

__global__ __launch_bounds__(256) void cvt_tr(CvtArgs a, u16* ws) {
  __shared__ u16 tile[128 * 136];
  const bool f32in = (((const u32*)a.in[11])[0] == 0x3F800000u);
  const int bid = blockIdx.x, tid = threadIdx.x;
  if (bid < 64) {
    WsPtrs w = wsp(ws);
    int tr = bid >> 3, tc = bid & 7;
#pragma unroll
    for (int p = 0; p < 8; ++p) {
      int t = p * 16 + (tid >> 4);
      int j8 = (tid & 15) * 8;
      u16 tmp[8];
      if (f32in) {
        const float* s = (const float*)a.in[5] + (size_t)(tr * 128 + t) * 1024 + tc * 128 + j8;
        float4 x = ((const float4*)s)[0], y = ((const float4*)s)[1];
        tmp[0]=f2bf(x.x); tmp[1]=f2bf(x.y); tmp[2]=f2bf(x.z); tmp[3]=f2bf(x.w);
        tmp[4]=f2bf(y.x); tmp[5]=f2bf(y.y); tmp[6]=f2bf(y.z); tmp[7]=f2bf(y.w);
      } else {
        *(uint4*)tmp = *(const uint4*)((const u16*)a.in[5] + (size_t)(tr * 128 + t) * 1024 + tc * 128 + j8);
      }
      *(uint4*)&tile[t * 136 + j8] = *(const uint4*)tmp;
    }
    __syncthreads();
#pragma unroll
    for (int p = 0; p < 8; ++p) {
      int j = p * 16 + (tid >> 4);
      int t8 = (tid & 15) * 8;
      u16 tmp[8];
#pragma unroll
      for (int i = 0; i < 8; ++i) tmp[i] = tile[(t8 + i) * 136 + j];
      *(uint4*)(w.woT + (size_t)(tc * 128 + j) * 1024 + tr * 128 + t8) = *(const uint4*)tmp;
    }
  } else {
    u32 c8 = (u32)(bid - 64) * 256u + tid;
    if (c8 < 2098432u) cvt_chunk(f32in, ws, a.in, c8);
  }
}

// ---------------- GEMM tile core, template TN in {128,64}, BK=64 ----------
// C[M,N] = A[M,K]*W[N,K]^T + bias. 128xTN tile, 4 waves (2x2), wave
// 64x(TN/2) via 4x(TN/32) mfma 16x16x32, 2 K-slices per step.
// LDS = 16KB(A) + TN*128 B(B). global_load_lds dwordx4 staging, XOR swizzle
// on SOURCE address (LDS dest linear, wave-uniform base); swizzled
// ds_read_b128 fragments, conflict-free.
// Modes: 0 bf16; 1 +relu bf16; 3 head-transpose (L=1<<lg); 4 v-transpose.
template <int TN>
__device__ __forceinline__ void gemm_core(
    u16* sA, u16* sB,
    const u16* A0, const u16* A1, int Ksplit, int lda0, int lda1,
    const u16* W, const u16* bias, void* out, int N, int K,
    int mode, int lg, int m0, int n0)
{
  constexpr int JN = TN >> 5;     // B frags per wave (4 or 2)
  constexpr int BCPT = TN >> 5;   // B chunks per thread (4 or 2)
  const int tid = threadIdx.x;
  const int wave = tid >> 6, lane = tid & 63;
  const int quad = lane >> 4, l16 = lane & 15;
  const int wm = wave >> 1, wn = wave & 1;

  f32x4 acc[4][JN];
#pragma unroll
  for (int i = 0; i < 4; ++i)
#pragma unroll
    for (int j = 0; j < JN; ++j) acc[i][j] = (f32x4){0.f, 0.f, 0.f, 0.f};

  for (int k0 = 0; k0 < K; k0 += 64) {
#pragma unroll
    for (int qi = 0; qi < 4; ++qi) {       // A: 128 rows x 8 chunks
      int p = (wave * 4 + qi) * 64 + lane;
      int row = p >> 3;
      int c = (p & 7) ^ (row & 7);
      int gk = k0 + (c << 3);
      const u16* srcA = (gk < Ksplit) ? (A0 + (size_t)(m0 + row) * lda0 + gk)
                                      : (A1 + (size_t)(m0 + row) * lda1 + (gk - Ksplit));
      __builtin_amdgcn_global_load_lds(
          (const __attribute__((address_space(1))) void*)srcA,
          (__attribute__((address_space(3))) void*)&sA[(size_t)(wave * 4 + qi) * 512],
          16, 0, 0);
    }
#pragma unroll
    for (int qi = 0; qi < BCPT; ++qi) {    // B: TN rows x 8 chunks
      int p = (wave * BCPT + qi) * 64 + lane;
      int row = p >> 3;
      int c = (p & 7) ^ (row & 7);
      int gk = k0 + (c << 3);
      const u16* srcB = W + (size_t)(n0 + row) * K + gk;
      __builtin_amdgcn_global_load_lds(
          (const __attribute__((address_space(1))) void*)srcB,
          (__attribute__((address_space(3))) void*)&sB[(size_t)(wave * BCPT + qi) * 512],
          16, 0, 0);
    }
    __syncthreads();
#pragma unroll
    for (int ks = 0; ks < 2; ++ks) {
      const int ch = (ks << 2) + quad;
      bf16x8 af[4], bw[JN];
#pragma unroll
      for (int i = 0; i < 4; ++i) {
        int row = wm * 64 + i * 16 + l16;
        af[i] = *(const bf16x8*)&sA[(row << 6) + ((ch ^ (row & 7)) << 3)];
      }
#pragma unroll
      for (int j = 0; j < JN; ++j) {
        int row = wn * (TN >> 1) + j * 16 + l16;
        bw[j] = *(const bf16x8*)&sB[(row << 6) + ((ch ^ (row & 7)) << 3)];
      }
#pragma unroll
      for (int i = 0; i < 4; ++i)
#pragma unroll
        for (int j = 0; j < JN; ++j)
          acc[i][j] = __builtin_amdgcn_mfma_f32_16x16x32_bf16(af[i], bw[j], acc[i][j], 0, 0, 0);
    }
    __syncthreads();
  }

  // C/D layout: col = l16, row = quad*4 + rr (verified m89/m91)
#pragma unroll
  for (int i = 0; i < 4; ++i) {
#pragma unroll
    for (int j = 0; j < JN; ++j) {
      int n = n0 + wn * (TN >> 1) + j * 16 + l16;
      float bv = bias ? bf2f(bias[n]) : 0.f;
#pragma unroll
      for (int rr = 0; rr < 4; ++rr) {
        int m = m0 + wm * 64 + i * 16 + quad * 4 + rr;
        float val = acc[i][j][rr] + bv;
        if (mode == 1) val = fmaxf(val, 0.f);
        if (mode <= 1) {
          ((u16*)out)[(size_t)m * N + n] = f2bf(val);
        } else if (mode == 3) {
          int b = m >> lg, l = m & ((1 << lg) - 1);
          int h = n >> 6, d = n & 63;
          ((u16*)out)[((size_t)((b * 16 + h)) << (lg + 6)) + (l << 6) + d] = f2bf(val);
        } else {
          int b = m >> lg, s = m & ((1 << lg) - 1);
          int h = n >> 6, d = n & 63;
          ((u16*)out)[((size_t)(((b * 16 + h) << 6) + d) << lg) + s] = f2bf(val);
        }
      }
    }
  }
}

// XCD chunked swizzle: blocks bid%8==c (one XCD under round-robin dispatch)
// get a contiguous u-range -> per-XCD L2 working set ~4MB. n%8==0 required.
__device__ __forceinline__ int xswz(int u, int n8) {  // n8 = nblk/8
  return (u & 7) * n8 + (u >> 3);
}

// P1: 836 blocks. 0..511 Q, 512..639 K, 640..767 V, 768..831 Wf, 832..835 bf.
__global__ __launch_bounds__(256, 4) void qkvwf(u16* ws) {
  __shared__ __align__(16) u16 lds[16384];
  WsPtrs w = wsp(ws);
  const int bid = blockIdx.x, tid = threadIdx.x;
  if (bid < 512) {
    int u = xswz(bid, 64);
    gemm_core<128>(lds, lds + 8192, w.c_mem, w.c_gaze, 512, 512, 512,
                   w.c_win, w.c_bin, w.q, 1024, 1024, 3, 10,
                   (u >> 3) * 128, (u & 7) * 128);
  } else if (bid < 640) {
    int u = xswz(bid - 512, 16);
    gemm_core<128>(lds, lds + 8192, w.c_text, w.c_text, 1024, 1024, 1024,
                   w.c_win + 1048576, w.c_bin + 1024, w.k, 1024, 1024, 3, 8,
                   (u >> 3) * 128, (u & 7) * 128);
  } else if (bid < 768) {
    int u = xswz(bid - 640, 16);
    gemm_core<128>(lds, lds + 8192, w.c_text, w.c_text, 1024, 1024, 1024,
                   w.c_win + 2097152, w.c_bin + 2048, w.v, 1024, 1024, 4, 8,
                   (u >> 3) * 128, (u & 7) * 128);
  } else if (bid < 832) {
    int u = xswz(bid - 768, 8);
    gemm_core<128>(lds, lds + 8192, w.c_w1, w.c_w1, 1024, 1024, 1024,
                   w.woT, nullptr, w.wf, 1024, 1024, 0, 0,
                   (u >> 3) * 128, (u & 7) * 128);
  } else {
    // bf[i] = b1[i] + sum_t W1[i,t]*bo[t]
    int i = (bid - 832) * 256 + tid;
    const u16* w1row = w.c_w1 + (size_t)i * 1024;
    float acc = bf2f(w.c_b1[i]);
    for (int kk = 0; kk < 1024; kk += 8) {
      bf16x8 wv = *(const bf16x8*)(w1row + kk);
      bf16x8 bv = *(const bf16x8*)(w.c_bo + kk);
#pragma unroll
      for (int j = 0; j < 8; ++j) acc += (float)wv[j] * (float)bv[j];
    }
    w.bfb[i] = f2bf(acc);
  }
}

// ---------------- P2: attention tile (b,h) x 64 queries (R13 form) --------
__global__ __launch_bounds__(256) void attn_kernel(u16* ws) {
  __shared__ u16 sV[64 * 256];
  __shared__ u16 sKP[256 * 64];
  WsPtrs w = wsp(ws);
  const int tid = threadIdx.x;
  const int wave = tid >> 6, lane = tid & 63;
  const int quad = lane >> 4, l16 = lane & 15;
  const int su = xswz(blockIdx.x, 256);   // 16 consecutive u share one K/V pair
  const int qb = su & 15, bh = su >> 4;

  {
    int rr = tid >> 3, c8 = (tid & 7) << 3;
    const u16* kb = w.k + (size_t)bh * 16384;
#pragma unroll
    for (int p = 0; p < 8; ++p) {
      int row = p * 32 + rr;
      uint4 val = *(const uint4*)(kb + row * 64 + c8);
      *(uint4*)&sKP[(row << 6) + ((((c8 >> 3) ^ (row & 7))) << 3)] = val;
    }
    int r2 = tid >> 5, c8b = (tid & 31) << 3;
    const u16* vb = w.v + (size_t)bh * 16384;
#pragma unroll
    for (int p = 0; p < 8; ++p) {
      int row = p * 8 + r2;
      uint4 val = *(const uint4*)(vb + (row << 8) + c8b);
      *(uint4*)&sV[(row << 8) + ((((c8b >> 3) ^ (row & 7))) << 3)] = val;
    }
  }
  bf16x8 aq[2];
  {
    const u16* qrow = w.q + ((size_t)bh * 1024 + qb * 64 + wave * 16 + l16) * 64 + quad * 8;
    aq[0] = *(const bf16x8*)(qrow);
    aq[1] = *(const bf16x8*)(qrow + 32);
  }
  __syncthreads();

  f32x4 sc[16];
#pragma unroll
  for (int nt = 0; nt < 16; ++nt) sc[nt] = (f32x4){0.f, 0.f, 0.f, 0.f};
  __builtin_amdgcn_s_setprio(1);
#pragma unroll
  for (int ks = 0; ks < 2; ++ks) {
    const int ch = (ks << 2) + quad;
#pragma unroll
    for (int nt = 0; nt < 16; ++nt) {
      int row = nt * 16 + l16;
      bf16x8 bk = *(const bf16x8*)&sKP[(row << 6) + ((ch ^ (row & 7)) << 3)];
      sc[nt] = __builtin_amdgcn_mfma_f32_16x16x32_bf16(aq[ks], bk, sc[nt], 0, 0, 0);
    }
  }
  __builtin_amdgcn_s_setprio(0);
#pragma unroll
  for (int rr = 0; rr < 4; ++rr) {
    float mx = -1e30f;
#pragma unroll
    for (int nt = 0; nt < 16; ++nt) mx = fmaxf(mx, sc[nt][rr]);
    for (int off = 1; off < 16; off <<= 1) mx = fmaxf(mx, __shfl_xor(mx, off, 64));
    float sum = 0.f;
#pragma unroll
    for (int nt = 0; nt < 16; ++nt) {
      float p = __expf((sc[nt][rr] - mx) * 0.125f);
      sc[nt][rr] = p; sum += p;
    }
    for (int off = 1; off < 16; off <<= 1) sum += __shfl_xor(sum, off, 64);
    float inv = 1.f / sum;
#pragma unroll
    for (int nt = 0; nt < 16; ++nt) sc[nt][rr] *= inv;
  }
  __syncthreads();
#pragma unroll
  for (int nt = 0; nt < 16; ++nt)
#pragma unroll
    for (int rr = 0; rr < 4; ++rr) {
      int row = wave * 16 + quad * 4 + rr;
      int col = nt * 16 + l16;
      sKP[(row << 8) + (((col >> 3) ^ (row & 7)) << 3) + (col & 7)] = f2bf(sc[nt][rr]);
    }
  __syncthreads();

  f32x4 o[4];
#pragma unroll
  for (int j = 0; j < 4; ++j) o[j] = (f32x4){0.f, 0.f, 0.f, 0.f};
  __builtin_amdgcn_s_setprio(1);
#pragma unroll
  for (int ks = 0; ks < 8; ++ks) {
    const int ch = (ks << 2) + quad;
    int prow = wave * 16 + l16;
    bf16x8 ap = *(const bf16x8*)&sKP[(prow << 8) + ((ch ^ (prow & 7)) << 3)];
#pragma unroll
    for (int j = 0; j < 4; ++j) {
      int vrow = j * 16 + l16;
      bf16x8 bv = *(const bf16x8*)&sV[(vrow << 8) + ((ch ^ (vrow & 7)) << 3)];
      o[j] = __builtin_amdgcn_mfma_f32_16x16x32_bf16(ap, bv, o[j], 0, 0, 0);
    }
  }
  __builtin_amdgcn_s_setprio(0);
  const int b = bh >> 4, h = bh & 15;
#pragma unroll
  for (int j = 0; j < 4; ++j)
#pragma unroll
    for (int rr = 0; rr < 4; ++rr) {
      int m = qb * 64 + wave * 16 + quad * 4 + rr;
      int d = h * 64 + j * 16 + l16;
      w.ctx[((size_t)b * 1024 + m) * 1024 + d] = f2bf(o[j][rr]);
    }
}

// P3: 1024 blocks. Each block: box for 8 rows (32-lane split-K) + one
// 128x64 h1 tile (BK=64, 24KB LDS, 4 blocks/CU).
__global__ __launch_bounds__(256, 4) void h1box(u16* ws, void* out, const void* g1orig) {
  __shared__ __align__(16) u16 lds[12288];
  WsPtrs w = wsp(ws);
  const int u = blockIdx.x, tid = threadIdx.x;
  {
    const bool f32out = (((const u32*)g1orig)[0] == 0x3F800000u);
    int m = u * 8 + (tid >> 5);
    int l32 = tid & 31;
    int k0 = l32 * 32;
    const u16* crow = w.ctx + (size_t)m * 1024 + k0;
    float a0 = 0.f, a1 = 0.f, a2 = 0.f, a3 = 0.f;
#pragma unroll
    for (int kk = 0; kk < 32; kk += 8) {
      bf16x8 cv = *(const bf16x8*)(crow + kk);
      bf16x8 w0 = *(const bf16x8*)(w.c_wo + k0 + kk);
      bf16x8 w1v = *(const bf16x8*)(w.c_wo + 1024 + k0 + kk);
      bf16x8 w2v = *(const bf16x8*)(w.c_wo + 2048 + k0 + kk);
      bf16x8 w3v = *(const bf16x8*)(w.c_wo + 3072 + k0 + kk);
#pragma unroll
      for (int j = 0; j < 8; ++j) {
        float c = (float)cv[j];
        a0 += c * (float)w0[j]; a1 += c * (float)w1v[j];
        a2 += c * (float)w2v[j]; a3 += c * (float)w3v[j];
      }
    }
    for (int off = 1; off < 32; off <<= 1) {
      a0 += __shfl_xor(a0, off, 64); a1 += __shfl_xor(a1, off, 64);
      a2 += __shfl_xor(a2, off, 64); a3 += __shfl_xor(a3, off, 64);
    }
    if (l32 == 0) {
      a0 += bf2f(w.c_bo[0]); a1 += bf2f(w.c_bo[1]);
      a2 += bf2f(w.c_bo[2]); a3 += bf2f(w.c_bo[3]);
      float s0 = 1.f / (1.f + __expf(-a0)), s1 = 1.f / (1.f + __expf(-a1));
      float s2 = 1.f / (1.f + __expf(-a2)), s3 = 1.f / (1.f + __expf(-a3));
      float o0 = s0 - s2 * 0.5f, o1 = s1 - s3 * 0.5f;
      float o2 = s0 + s2 * 0.5f, o3 = s1 + s3 * 0.5f;
      if (f32out) {
        float* fo = (float*)out + 16777216;
        *(float4*)(fo + (size_t)m * 4) = make_float4(o0, o1, o2, o3);
      } else {
        u16* bo = (u16*)out + 16777216;
        u16x4 o; o[0] = f2bf(o0); o[1] = f2bf(o1); o[2] = f2bf(o2); o[3] = f2bf(o3);
        *(u16x4*)(bo + (size_t)m * 4) = o;
      }
    }
  }
  int us = xswz(u, 128);
  gemm_core<64>(lds, lds + 8192, w.ctx, w.ctx, 1024, 1024, 1024,
                w.wf, w.bfb, w.h1, 1024, 1024, 1, 0,
                (us >> 4) * 128, (us & 15) * 64);
}

// P4: ffnb = h1 @ w2^T + b2 (bf16 out). 1024 blocks, 128x64 tiles.
__global__ __launch_bounds__(256, 4) void w2gemm(u16* ws) {
  __shared__ __align__(16) u16 lds[12288];
  WsPtrs w = wsp(ws);
  int us = xswz((int)blockIdx.x, 128);
  gemm_core<64>(lds, lds + 8192, w.h1, w.h1, 1024, 1024, 1024,
                w.c_w2, w.c_b2, w.ffnb, 1024, 1024, 0, 0,
                (us >> 4) * 128, (us & 15) * 64);
}

// P5: LayerNorm x2 over ffnb bf16 [8192][1024]; dual-dtype output.
__global__ __launch_bounds__(256) void ln_kernel(u16* ws, void* outv, const void* g1orig) {
  WsPtrs w = wsp(ws);
  const bool f32out = (((const u32*)g1orig)[0] == 0x3F800000u);
  const int row = blockIdx.x, tid = threadIdx.x;
  int c = tid * 4;
  u16x4 xr = *(const u16x4*)(w.ffnb + (size_t)row * 1024 + c);
  float x[4] = {bf2f(xr[0]), bf2f(xr[1]), bf2f(xr[2]), bf2f(xr[3])};
  float s = x[0] + x[1] + x[2] + x[3];
  float s2 = x[0]*x[0] + x[1]*x[1] + x[2]*x[2] + x[3]*x[3];
  for (int m = 32; m >= 1; m >>= 1) { s += __shfl_xor(s, m, 64); s2 += __shfl_xor(s2, m, 64); }
  __shared__ float red[8];
  int wv = tid >> 6;
  if ((tid & 63) == 0) { red[wv] = s; red[4 + wv] = s2; }
  __syncthreads();
  s = red[0] + red[1] + red[2] + red[3];
  s2 = red[4] + red[5] + red[6] + red[7];
  float mean = s * (1.f / 1024.f);
  float var = s2 * (1.f / 1024.f) - mean * mean;
  float inv = rsqrtf(var + 1e-5f);
  float y[4] = {(x[0] - mean) * inv, (x[1] - mean) * inv, (x[2] - mean) * inv, (x[3] - mean) * inv};
  float v1[4], v2[4];
#pragma unroll
  for (int i = 0; i < 4; ++i) {
    v1[i] = y[i] * bf2f(w.c_g1[c + i]) + bf2f(w.c_be1[c + i]);
    v2[i] = y[i] * bf2f(w.c_g2[c + i]) + bf2f(w.c_be2[c + i]);
  }
  if (f32out) {
    float* fo = (float*)outv;
    *(float4*)(fo + (size_t)row * 1024 + c) = make_float4(v1[0], v1[1], v1[2], v1[3]);
    *(float4*)(fo + 8388608 + (size_t)row * 1024 + c) = make_float4(v2[0], v2[1], v2[2], v2[3]);
  } else {
    u16* out = (u16*)outv;
    u16x4 o1, o2;
#pragma unroll
    for (int i = 0; i < 4; ++i) { o1[i] = f2bf(v1[i]); o2[i] = f2bf(v2[i]); }
    *(u16x4*)(out + (size_t)row * 1024 + c) = o1;
    *(u16x4*)(out + 8388608 + (size_t)row * 1024 + c) = o2;
  }
}

extern "C" void kernel_launch(void* const* d_in, const int* in_sizes, int n_in,
                              void* d_out, int out_size, void* d_ws, size_t ws_size,
                              hipStream_t stream) {
  CvtArgs ca;
  for (int i = 0; i < 15; ++i) ca.in[i] = d_in[i];
  u16* ws = (u16*)d_ws;
  dim3 blk(256);
  cvt_tr<<<dim3(8261), blk, 0, stream>>>(ca, ws);
  qkvwf<<<dim3(836), blk, 0, stream>>>(ws);
  attn_kernel<<<dim3(2048), blk, 0, stream>>>(ws);
  h1box<<<dim3(1024), blk, 0, stream>>>(ws, d_out, d_in[11]);
  w2gemm<<<dim3(1024), blk, 0, stream>>>(ws);
  ln_kernel<<<dim3(8192), blk, 0, stream>>>(ws, d_out, d_in[11]);
}